// Round 4
// baseline (1142.333 us; speedup 1.0000x reference)
//
#include <hip/hip_runtime.h>
#include <hip/hip_bf16.h>

typedef __attribute__((ext_vector_type(8))) short short8;
typedef __attribute__((ext_vector_type(4))) short short4v;
typedef __attribute__((ext_vector_type(4))) float f32x4;

#define VOXELS 262144  // 64^3
#define F_PAD  872     // 864 + 8
#define ZC_PAD 264     // 256 + 8
#define Z0_PAD 72      // 64 + 8
#define Z2_PAD 520     // 512 + 8
#define Z3_PAD 264     // 256 + 8

// ---------------- volume transpose: (C,D,H,W) -> (D,H,W,C) ----------------
template <bool VT16>
__global__ void k_transpose(const float* __restrict__ v0, const float* __restrict__ v1,
                            const float* __restrict__ v2, const float* __restrict__ v3,
                            void* __restrict__ vtp) {
    int b  = blockIdx.x;
    int q  = b >> 12;          // 4096 (z,y) rows per volume
    int zy = b & 4095;
    const float* src = (q == 0) ? v0 : (q == 1) ? v1 : (q == 2) ? v2 : v3;
    __shared__ float buf[32][65];
    int t = threadIdx.x;
    int x = t & 63, c0 = t >> 6;
    for (int cp = 0; cp < 32; cp += 4) {
        int c = c0 + cp;
        buf[c][x] = src[(size_t)c * VOXELS + (size_t)zy * 64 + x];
    }
    __syncthreads();
    int c = t & 31, xg = t >> 5;
    const size_t base = ((size_t)q * VOXELS + (size_t)zy * 64) * 32;
    for (int xx = xg; xx < 64; xx += 8) {
        if (VT16) ((__hip_bfloat16*)vtp)[base + xx * 32 + c] = __float2bfloat16(buf[c][xx]);
        else      ((float*)vtp)[base + xx * 32 + c] = buf[c][xx];
    }
}

// ------------- weight pack: W[O][K] fp32 -> bf16 MFMA-B fragment order -------------
__global__ void k_prepw(const float* __restrict__ W, __hip_bfloat16* __restrict__ wf,
                        int O, int K, int conv_remap) {
    int n = blockIdx.x * blockDim.x + threadIdx.x;
    if (n >= O * K) return;
    int e = n & 7, lane = (n >> 3) & 63;
    int rest = n >> 9;
    int ksteps = K >> 5;
    int kstep = rest % ksteps, otile = rest / ksteps;
    int o = otile * 16 + (lane & 15);
    int k = kstep * 32 + (lane >> 4) * 8 + e;
    int ksrc = conv_remap ? ((k & 31) * 27 + (k >> 5)) : k;
    wf[n] = __float2bfloat16(W[(size_t)o * K + ksrc]);
}

// ============ standalone sampler: 1 point/wave, 4 waves/block, no LDS ============
// Corner-per-lane: g=lane&7 -> 4 channels; bits 3/4/5 -> trilinear corner.
// Per-axis offsets/weights hoisted per (q,pos) and pre-selected by corner bit.
template <bool VT16>
__global__ __launch_bounds__(256, 8)
void k_sample(const float* __restrict__ xin, const void* __restrict__ vtp,
              __hip_bfloat16* __restrict__ fbuf, int m) {
    const int lane = threadIdx.x & 63;
    const int p = blockIdx.x * 4 + (threadIdx.x >> 6);
    if (p >= m) return;

    const float px = xin[p * 3 + 0];
    const float py = xin[p * 3 + 1];
    const float pz = xin[p * 3 + 2];

    const int g  = lane & 7;
    const int cx = (lane >> 3) & 1;
    const int cy = (lane >> 4) & 1;
    const int cz = (lane >> 5) & 1;

    const float pxs = px * 31.5f + 31.5f;
    const float pys = py * 31.5f + 31.5f;
    const float pzs = pz * 31.5f + 31.5f;

    // byte-offset shifts, channel-last: idx = ((z*64+y)*64+x)*32ch*elt + g*4*elt
    const int XS = VT16 ? 6 : 7;
    const int YS = VT16 ? 12 : 13;
    const int ZS = VT16 ? 18 : 19;
    const int QS = VT16 ? 24 : 25;
    const int GB = VT16 ? 8 : 16;

    int   xoS[4][3], yoS[4][3], zoS[4][3];
    float wxS[4][3], wyS[4][3], wzS[4][3];
#pragma unroll
    for (int q = 0; q < 4; ++q) {
        const float sc31 = (float)(2 << q) * (31.5f / 64.0f);
#pragma unroll
        for (int pos = 0; pos < 3; ++pos) {
            const float gv = (-2.0f + 1.5f * (float)pos) * sc31;  // compile-time
            {
                float ix = fminf(fmaxf(pxs + gv, 0.f), 63.f);
                float xf = floorf(ix); int x0 = (int)xf; float fx = ix - xf;
                int x1 = min(x0 + 1, 63);
                xoS[q][pos] = ((cx ? x1 : x0) << XS) + g * GB;
                wxS[q][pos] = cx ? fx : 1.f - fx;
            }
            {
                float iy = fminf(fmaxf(pys + gv, 0.f), 63.f);
                float yf = floorf(iy); int y0 = (int)yf; float fy = iy - yf;
                int y1 = min(y0 + 1, 63);
                yoS[q][pos] = (cy ? y1 : y0) << YS;
                wyS[q][pos] = cy ? fy : 1.f - fy;
            }
            {
                float iz = fminf(fmaxf(pzs + gv, 0.f), 63.f);
                float zf = floorf(iz); int z0 = (int)zf; float fz = iz - zf;
                int z1 = min(z0 + 1, 63);
                zoS[q][pos] = ((cz ? z1 : z0) << ZS) + (q << QS);
                wzS[q][pos] = cz ? fz : 1.f - fz;
            }
        }
    }

    const char* __restrict__ vtb = (const char*)vtp;
    __hip_bfloat16* __restrict__ frow = fbuf + (size_t)p * 864;
#pragma unroll
    for (int j = 0; j < 3; ++j)
#pragma unroll
    for (int i = 0; i < 3; ++i)
#pragma unroll
    for (int k = 0; k < 3; ++k) {
        f32x4 acc = {0.f, 0.f, 0.f, 0.f};
#pragma unroll
        for (int q = 0; q < 4; ++q) {
            const int addr = zoS[q][k] + yoS[q][i] + xoS[q][j];
            f32x4 v;
            if (VT16) {
                short4v raw = *(const short4v*)(vtb + addr);
#pragma unroll
                for (int e = 0; e < 4; ++e)
                    v[e] = __uint_as_float(((unsigned)(unsigned short)raw[e]) << 16);
            } else {
                v = *(const f32x4*)(vtb + addr);
            }
            const float w = wzS[q][k] * wyS[q][i] * wxS[q][j];
#pragma unroll
            for (int r = 0; r < 4; ++r) acc[r] += w * v[r];
        }
#pragma unroll
        for (int r = 0; r < 4; ++r) {
            acc[r] += __shfl_xor(acc[r], 8);
            acc[r] += __shfl_xor(acc[r], 16);
            acc[r] += __shfl_xor(acc[r], 32);
        }
        if (lane < 8) {
            union { short4v v; __hip_bfloat16 h[4]; } u;
#pragma unroll
            for (int e = 0; e < 4; ++e) u.h[e] = __float2bfloat16(acc[e]);
            *(short4v*)(frow + (j * 9 + i * 3 + k) * 32 + lane * 4) = u.v;
        }
    }
}

// ============ MLP kernel: 16 points/block; conv A-fragments read from fbuf ============
__global__ __launch_bounds__(1024, 8)
void k_mlp(const float* __restrict__ xin, const __hip_bfloat16* __restrict__ fbuf,
           const __hip_bfloat16* __restrict__ w0f, const float* __restrict__ b0,
           const __hip_bfloat16* __restrict__ w1f, const float* __restrict__ b1,
           const float* __restrict__ fc1w, const float* __restrict__ fc1b,
           const __hip_bfloat16* __restrict__ w2f, const float* __restrict__ b2,
           const __hip_bfloat16* __restrict__ w3f, const float* __restrict__ b3,
           const float* __restrict__ fc4w, const float* __restrict__ fc4b,
           float* __restrict__ out, int m) {
    __shared__ __align__(16) __hip_bfloat16 zcat[16][ZC_PAD];
    __shared__ __align__(16) __hip_bfloat16 z0l[16][Z0_PAD];
    __shared__ __align__(16) __hip_bfloat16 z2l[16][Z2_PAD];
    __shared__ __align__(16) __hip_bfloat16 z3l[16][Z3_PAD];

    const int tid  = threadIdx.x;
    const int wave = tid >> 6;
    const int lane = tid & 63;
    const int p0   = blockIdx.x * 16;

    // ---- z_point = leaky(x @ fc1^T + b) -> zcat[:,0:128] ----
    {
        const int ptp = tid >> 6;
        const int ob  = tid & 63;
        const int p   = min(p0 + ptp, m - 1);
        const float qx = xin[p * 3 + 0], qy = xin[p * 3 + 1], qz = xin[p * 3 + 2];
#pragma unroll
        for (int r = 0; r < 2; ++r) {
            const int o = ob + 64 * r;
            float v = qx * fc1w[o * 3 + 0] + qy * fc1w[o * 3 + 1] + qz * fc1w[o * 3 + 2] + fc1b[o];
            v = fmaxf(v, 0.2f * v);
            zcat[ptp][o] = __float2bfloat16(v);
        }
    }

    // ---- conv GEMM [16x864]x[864x64] (waves 0..3), A from global fbuf ----
    if (wave < 4) {
        f32x4 acc = {0.f, 0.f, 0.f, 0.f};
        const int row = lane & 15, g = lane >> 4;
        const int pr = min(p0 + row, m - 1);
        const __hip_bfloat16* arow = fbuf + (size_t)pr * 864;
        for (int ks = 0; ks < 27; ++ks) {
            short8 af = *(const short8*)(arow + ks * 32 + g * 8);
            short8 bf = *(const short8*)(w0f + (((size_t)wave * 27 + ks) * 64 + lane) * 8);
            acc = __builtin_amdgcn_mfma_f32_16x16x32_bf16(af, bf, acc, 0, 0, 0);
        }
        const int o = wave * 16 + row;
        const float bias = b0[o];
#pragma unroll
        for (int r = 0; r < 4; ++r)
            z0l[g * 4 + r][o] = __float2bfloat16(acc[r] + bias);
    }
    __syncthreads();

    // ---- lfc GEMM [16x64]x[64x128] (waves 0..7) -> zcat[:,128:256] ----
    if (wave < 8) {
        f32x4 acc = {0.f, 0.f, 0.f, 0.f};
        const int row = lane & 15, g = lane >> 4;
#pragma unroll
        for (int ks = 0; ks < 2; ++ks) {
            short8 af = *(const short8*)&z0l[row][ks * 32 + g * 8];
            short8 bf = *(const short8*)(w1f + (((size_t)wave * 2 + ks) * 64 + lane) * 8);
            acc = __builtin_amdgcn_mfma_f32_16x16x32_bf16(af, bf, acc, 0, 0, 0);
        }
        const int o = wave * 16 + row;
        const float bias = b1[o];
#pragma unroll
        for (int r = 0; r < 4; ++r)
            zcat[g * 4 + r][128 + o] = __float2bfloat16(acc[r] + bias);
    }
    __syncthreads();

    // ---- fc2 [16x256]x[256x512], leaky (16 waves x 2 tiles) ----
    {
        const int row = lane & 15, g = lane >> 4;
#pragma unroll
        for (int rt = 0; rt < 2; ++rt) {
            const int tile = wave * 2 + rt;
            f32x4 acc = {0.f, 0.f, 0.f, 0.f};
#pragma unroll
            for (int ks = 0; ks < 8; ++ks) {
                short8 af = *(const short8*)&zcat[row][ks * 32 + g * 8];
                short8 bf = *(const short8*)(w2f + (((size_t)tile * 8 + ks) * 64 + lane) * 8);
                acc = __builtin_amdgcn_mfma_f32_16x16x32_bf16(af, bf, acc, 0, 0, 0);
            }
            const int o = tile * 16 + row;
            const float bias = b2[o];
#pragma unroll
            for (int r = 0; r < 4; ++r) {
                float v = acc[r] + bias;
                v = fmaxf(v, 0.2f * v);
                z2l[g * 4 + r][o] = __float2bfloat16(v);
            }
        }
    }
    __syncthreads();

    // ---- fc3 [16x512]x[512x256], leaky (wave = tile) ----
    {
        const int row = lane & 15, g = lane >> 4;
        f32x4 acc = {0.f, 0.f, 0.f, 0.f};
        for (int ks = 0; ks < 16; ++ks) {
            short8 af = *(const short8*)&z2l[row][ks * 32 + g * 8];
            short8 bf = *(const short8*)(w3f + (((size_t)wave * 16 + ks) * 64 + lane) * 8);
            acc = __builtin_amdgcn_mfma_f32_16x16x32_bf16(af, bf, acc, 0, 0, 0);
        }
        const int o = wave * 16 + row;
        const float bias = b3[o];
#pragma unroll
        for (int r = 0; r < 4; ++r) {
            float v = acc[r] + bias;
            v = fmaxf(v, 0.2f * v);
            z3l[g * 4 + r][o] = __float2bfloat16(v);
        }
    }
    __syncthreads();

    // ---- fc4 [16x256]x[256x3] (waves 0..2, o = wave) ----
    if (wave < 3) {
        const int ptq = lane & 15, kg = lane >> 4;
        const int o = wave;
        float s = 0.f;
        for (int kk = 0; kk < 64; ++kk) {
            const int k = kg * 64 + kk;
            s += __bfloat162float(z3l[ptq][k]) * fc4w[o * 256 + k];
        }
        s += __shfl_xor(s, 16);
        s += __shfl_xor(s, 32);
        if (kg == 0) {
            const int pg = p0 + ptq;
            if (pg < m) out[pg * 3 + o] = s + fc4b[o];
        }
    }
}

// ================= fused fallback (round-3 kernel, fp32 channel-last) =================
template <bool CHLAST>
__global__ __launch_bounds__(1024, 4)
void k_fused(const float* __restrict__ xin, const float* __restrict__ vt,
             const float* __restrict__ v0, const float* __restrict__ v1,
             const float* __restrict__ v2, const float* __restrict__ v3,
             const __hip_bfloat16* __restrict__ w0f, const float* __restrict__ b0,
             const __hip_bfloat16* __restrict__ w1f, const float* __restrict__ b1,
             const float* __restrict__ fc1w, const float* __restrict__ fc1b,
             const __hip_bfloat16* __restrict__ w2f, const float* __restrict__ b2,
             const __hip_bfloat16* __restrict__ w3f, const float* __restrict__ b3,
             const float* __restrict__ fc4w, const float* __restrict__ fc4b,
             float* __restrict__ out, int m) {
    __shared__ __align__(16) __hip_bfloat16 f_lds[16][F_PAD];
    __shared__ __align__(16) __hip_bfloat16 zcat[16][ZC_PAD];
    __shared__ __align__(16) __hip_bfloat16 z0l[16][Z0_PAD];
    __shared__ __align__(16) __hip_bfloat16 z2l[16][Z2_PAD];
    __shared__ __align__(16) __hip_bfloat16 z3l[16][Z3_PAD];
    __shared__ float ptl[16][3];

    const int tid  = threadIdx.x;
    const int wave = tid >> 6;
    const int lane = tid & 63;
    const int p0   = blockIdx.x * 16;

    {
        const int pt = wave;
        const int p  = min(p0 + pt, m - 1);
        const float px = xin[p * 3 + 0];
        const float py = xin[p * 3 + 1];
        const float pz = xin[p * 3 + 2];
        if (lane == 0) { ptl[pt][0] = px; ptl[pt][1] = py; ptl[pt][2] = pz; }

        const int g  = lane & 7;
        const int cx = (lane >> 3) & 1;
        const int cy = (lane >> 4) & 1;
        const int cz = (lane >> 5) & 1;

        const float pxs = px * 31.5f + 31.5f;
        const float pys = py * 31.5f + 31.5f;
        const float pzs = pz * 31.5f + 31.5f;

        const int XS = CHLAST ? 7 : 2;
        const int YS = CHLAST ? 13 : 8;
        const int ZS = CHLAST ? 19 : 14;

        int   xoS[4][3], yoS[4][3], zoS[4][3];
        float wxS[4][3], wyS[4][3], wzS[4][3];
#pragma unroll
        for (int q = 0; q < 4; ++q) {
            const float sc31 = (float)(2 << q) * (31.5f / 64.0f);
#pragma unroll
            for (int pos = 0; pos < 3; ++pos) {
                const float gv = (-2.0f + 1.5f * (float)pos) * sc31;
                {
                    float ix = fminf(fmaxf(pxs + gv, 0.f), 63.f);
                    float xf = floorf(ix); int x0 = (int)xf; float fx = ix - xf;
                    int x1 = min(x0 + 1, 63);
                    xoS[q][pos] = ((cx ? x1 : x0) << XS) + (CHLAST ? g * 16 : 0);
                    wxS[q][pos] = cx ? fx : 1.f - fx;
                }
                {
                    float iy = fminf(fmaxf(pys + gv, 0.f), 63.f);
                    float yf = floorf(iy); int y0 = (int)yf; float fy = iy - yf;
                    int y1 = min(y0 + 1, 63);
                    yoS[q][pos] = (cy ? y1 : y0) << YS;
                    wyS[q][pos] = cy ? fy : 1.f - fy;
                }
                {
                    float iz = fminf(fmaxf(pzs + gv, 0.f), 63.f);
                    float zf = floorf(iz); int z0 = (int)zf; float fz = iz - zf;
                    int z1 = min(z0 + 1, 63);
                    zoS[q][pos] = ((cz ? z1 : z0) << ZS) + (CHLAST ? q * 33554432 : 0);
                    wzS[q][pos] = cz ? fz : 1.f - fz;
                }
            }
        }

        const char* __restrict__ vtb = (const char*)vt;
#pragma unroll
        for (int j = 0; j < 3; ++j)
#pragma unroll
        for (int i = 0; i < 3; ++i)
#pragma unroll
        for (int k = 0; k < 3; ++k) {
            f32x4 acc = {0.f, 0.f, 0.f, 0.f};
#pragma unroll
            for (int q = 0; q < 4; ++q) {
                const int addr = zoS[q][k] + yoS[q][i] + xoS[q][j];
                f32x4 v;
                if (CHLAST) {
                    v = *(const f32x4*)(vtb + addr);
                } else {
                    const char* vqb = (const char*)((q == 0) ? v0 : (q == 1) ? v1
                                                   : (q == 2) ? v2 : v3);
#pragma unroll
                    for (int e = 0; e < 4; ++e)
                        v[e] = *(const float*)(vqb + addr + (size_t)(g * 4 + e) * (VOXELS * 4));
                }
                const float w = wzS[q][k] * wyS[q][i] * wxS[q][j];
#pragma unroll
                for (int r = 0; r < 4; ++r) acc[r] += w * v[r];
            }
#pragma unroll
            for (int r = 0; r < 4; ++r) {
                acc[r] += __shfl_xor(acc[r], 8);
                acc[r] += __shfl_xor(acc[r], 16);
                acc[r] += __shfl_xor(acc[r], 32);
            }
            if (lane < 8) {
                const int col = (j * 9 + i * 3 + k) * 32 + lane * 4;
#pragma unroll
                for (int e = 0; e < 4; ++e)
                    f_lds[pt][col + e] = __float2bfloat16(acc[e]);
            }
        }
    }
    __syncthreads();

    {
        const int ptp = tid >> 6;
        const int ob  = tid & 63;
        const float qx = ptl[ptp][0], qy = ptl[ptp][1], qz = ptl[ptp][2];
#pragma unroll
        for (int r = 0; r < 2; ++r) {
            const int o = ob + 64 * r;
            float v = qx * fc1w[o * 3 + 0] + qy * fc1w[o * 3 + 1] + qz * fc1w[o * 3 + 2] + fc1b[o];
            v = fmaxf(v, 0.2f * v);
            zcat[ptp][o] = __float2bfloat16(v);
        }
    }

    if (wave < 4) {
        f32x4 acc = {0.f, 0.f, 0.f, 0.f};
        const int row = lane & 15, g = lane >> 4;
        for (int ks = 0; ks < 27; ++ks) {
            short8 af = *(const short8*)&f_lds[row][ks * 32 + g * 8];
            short8 bf = *(const short8*)(w0f + (((size_t)wave * 27 + ks) * 64 + lane) * 8);
            acc = __builtin_amdgcn_mfma_f32_16x16x32_bf16(af, bf, acc, 0, 0, 0);
        }
        const int o = wave * 16 + row;
        const float bias = b0[o];
#pragma unroll
        for (int r = 0; r < 4; ++r)
            z0l[g * 4 + r][o] = __float2bfloat16(acc[r] + bias);
    }
    __syncthreads();

    if (wave < 8) {
        f32x4 acc = {0.f, 0.f, 0.f, 0.f};
        const int row = lane & 15, g = lane >> 4;
#pragma unroll
        for (int ks = 0; ks < 2; ++ks) {
            short8 af = *(const short8*)&z0l[row][ks * 32 + g * 8];
            short8 bf = *(const short8*)(w1f + (((size_t)wave * 2 + ks) * 64 + lane) * 8);
            acc = __builtin_amdgcn_mfma_f32_16x16x32_bf16(af, bf, acc, 0, 0, 0);
        }
        const int o = wave * 16 + row;
        const float bias = b1[o];
#pragma unroll
        for (int r = 0; r < 4; ++r)
            zcat[g * 4 + r][128 + o] = __float2bfloat16(acc[r] + bias);
    }
    __syncthreads();

    {
        const int row = lane & 15, g = lane >> 4;
#pragma unroll
        for (int rt = 0; rt < 2; ++rt) {
            const int tile = wave * 2 + rt;
            f32x4 acc = {0.f, 0.f, 0.f, 0.f};
#pragma unroll
            for (int ks = 0; ks < 8; ++ks) {
                short8 af = *(const short8*)&zcat[row][ks * 32 + g * 8];
                short8 bf = *(const short8*)(w2f + (((size_t)tile * 8 + ks) * 64 + lane) * 8);
                acc = __builtin_amdgcn_mfma_f32_16x16x32_bf16(af, bf, acc, 0, 0, 0);
            }
            const int o = tile * 16 + row;
            const float bias = b2[o];
#pragma unroll
            for (int r = 0; r < 4; ++r) {
                float v = acc[r] + bias;
                v = fmaxf(v, 0.2f * v);
                z2l[g * 4 + r][o] = __float2bfloat16(v);
            }
        }
    }
    __syncthreads();

    {
        const int row = lane & 15, g = lane >> 4;
        f32x4 acc = {0.f, 0.f, 0.f, 0.f};
        for (int ks = 0; ks < 16; ++ks) {
            short8 af = *(const short8*)&z2l[row][ks * 32 + g * 8];
            short8 bf = *(const short8*)(w3f + (((size_t)wave * 16 + ks) * 64 + lane) * 8);
            acc = __builtin_amdgcn_mfma_f32_16x16x32_bf16(af, bf, acc, 0, 0, 0);
        }
        const int o = wave * 16 + row;
        const float bias = b3[o];
#pragma unroll
        for (int r = 0; r < 4; ++r) {
            float v = acc[r] + bias;
            v = fmaxf(v, 0.2f * v);
            z3l[g * 4 + r][o] = __float2bfloat16(v);
        }
    }
    __syncthreads();

    if (wave < 3) {
        const int ptq = lane & 15, kg = lane >> 4;
        const int o = wave;
        float s = 0.f;
        for (int kk = 0; kk < 64; ++kk) {
            const int k = kg * 64 + kk;
            s += __bfloat162float(z3l[ptq][k]) * fc4w[o * 256 + k];
        }
        s += __shfl_xor(s, 16);
        s += __shfl_xor(s, 32);
        if (kg == 0) {
            const int pg = p0 + ptq;
            if (pg < m) out[pg * 3 + o] = s + fc4b[o];
        }
    }
}

extern "C" void kernel_launch(void* const* d_in, const int* in_sizes, int n_in,
                              void* d_out, int out_size, void* d_ws, size_t ws_size,
                              hipStream_t stream) {
    const float* x      = (const float*)d_in[1];
    const float* v0     = (const float*)d_in[2];
    const float* v1     = (const float*)d_in[3];
    const float* v2     = (const float*)d_in[4];
    const float* v3     = (const float*)d_in[5];
    const float* conv_w = (const float*)d_in[6];
    const float* conv_b = (const float*)d_in[7];
    const float* lfc_w  = (const float*)d_in[8];
    const float* lfc_b  = (const float*)d_in[9];
    const float* fc1_w  = (const float*)d_in[10];
    const float* fc1_b  = (const float*)d_in[11];
    const float* fc2_w  = (const float*)d_in[12];
    const float* fc2_b  = (const float*)d_in[13];
    const float* fc3_w  = (const float*)d_in[14];
    const float* fc3_b  = (const float*)d_in[15];
    const float* fc4_w  = (const float*)d_in[16];
    const float* fc4_b  = (const float*)d_in[17];
    float* out = (float*)d_out;
    const int m = in_sizes[1] / 3;

    char* ws = (char*)d_ws;
    size_t woff = 0;
    __hip_bfloat16* w0f = (__hip_bfloat16*)(ws + woff); woff += (size_t)55296 * 2;
    __hip_bfloat16* w1f = (__hip_bfloat16*)(ws + woff); woff += (size_t)8192 * 2;
    __hip_bfloat16* w2f = (__hip_bfloat16*)(ws + woff); woff += (size_t)131072 * 2;
    __hip_bfloat16* w3f = (__hip_bfloat16*)(ws + woff); woff += (size_t)131072 * 2;
    woff = (woff + 255) & ~(size_t)255;

    const size_t vt32_bytes = (size_t)4 * VOXELS * 32 * 4;   // 128 MiB
    const size_t vt16_bytes = (size_t)4 * VOXELS * 32 * 2;   // 64 MiB
    const size_t fbytes     = ((size_t)m * 864 * 2 + 255) & ~(size_t)255;

    const size_t need_split32 = woff + vt32_bytes + fbytes;
    const size_t need_split16 = woff + vt16_bytes + fbytes;
    const size_t need_fused32 = woff + vt32_bytes;

    k_prepw<<<(55296 + 255) / 256, 256, 0, stream>>>(conv_w, w0f, 64, 864, 1);
    k_prepw<<<(8192 + 255) / 256, 256, 0, stream>>>(lfc_w, w1f, 128, 64, 0);
    k_prepw<<<(131072 + 255) / 256, 256, 0, stream>>>(fc2_w, w2f, 512, 256, 0);
    k_prepw<<<(131072 + 255) / 256, 256, 0, stream>>>(fc3_w, w3f, 256, 512, 0);

    const int nsb = (m + 3) / 4;
    const int nb  = (m + 15) / 16;

    if (ws_size >= need_split32) {
        void* vt = (void*)(ws + woff);
        __hip_bfloat16* fbuf = (__hip_bfloat16*)(ws + woff + vt32_bytes);
        k_transpose<false><<<16384, 256, 0, stream>>>(v0, v1, v2, v3, vt);
        k_sample<false><<<nsb, 256, 0, stream>>>(x, vt, fbuf, m);
        k_mlp<<<nb, 1024, 0, stream>>>(x, fbuf, w0f, conv_b, w1f, lfc_b, fc1_w, fc1_b,
                                       w2f, fc2_b, w3f, fc3_b, fc4_w, fc4_b, out, m);
    } else if (ws_size >= need_split16) {
        void* vt = (void*)(ws + woff);
        __hip_bfloat16* fbuf = (__hip_bfloat16*)(ws + woff + vt16_bytes);
        k_transpose<true><<<16384, 256, 0, stream>>>(v0, v1, v2, v3, vt);
        k_sample<true><<<nsb, 256, 0, stream>>>(x, vt, fbuf, m);
        k_mlp<<<nb, 1024, 0, stream>>>(x, fbuf, w0f, conv_b, w1f, lfc_b, fc1_w, fc1_b,
                                       w2f, fc2_b, w3f, fc3_b, fc4_w, fc4_b, out, m);
    } else if (ws_size >= need_fused32) {
        float* vt = (float*)(ws + woff);
        k_transpose<false><<<16384, 256, 0, stream>>>(v0, v1, v2, v3, (void*)vt);
        k_fused<true><<<nb, 1024, 0, stream>>>(x, vt, v0, v1, v2, v3,
                                               w0f, conv_b, w1f, lfc_b, fc1_w, fc1_b,
                                               w2f, fc2_b, w3f, fc3_b, fc4_w, fc4_b, out, m);
    } else {
        k_fused<false><<<nb, 1024, 0, stream>>>(x, nullptr, v0, v1, v2, v3,
                                                w0f, conv_b, w1f, lfc_b, fc1_w, fc1_b,
                                                w2f, fc2_b, w3f, fc3_b, fc4_w, fc4_b, out, m);
    }
}

// Round 5
// 808.068 us; speedup vs baseline: 1.4137x; 1.4137x over previous
//
#include <hip/hip_runtime.h>
#include <hip/hip_bf16.h>

typedef __attribute__((ext_vector_type(8))) short short8;
typedef __attribute__((ext_vector_type(4))) short short4v;
typedef __attribute__((ext_vector_type(4))) float f32x4;

#define VOXELS 262144  // 64^3
#define F_PAD  872
#define ZC_PAD 264
#define Z0_PAD 72
#define Z2_PAD 520
#define Z3_PAD 264
#define NCELL  512     // 8x8x8 Morton cells

// ---------------- volume transpose: (C,D,H,W) -> (D,H,W,C) ----------------
template <bool VT16>
__global__ void k_transpose(const float* __restrict__ v0, const float* __restrict__ v1,
                            const float* __restrict__ v2, const float* __restrict__ v3,
                            void* __restrict__ vtp) {
    int b  = blockIdx.x;
    int q  = b >> 12;
    int zy = b & 4095;
    const float* src = (q == 0) ? v0 : (q == 1) ? v1 : (q == 2) ? v2 : v3;
    __shared__ float buf[32][65];
    int t = threadIdx.x;
    int x = t & 63, c0 = t >> 6;
    for (int cp = 0; cp < 32; cp += 4) {
        int c = c0 + cp;
        buf[c][x] = src[(size_t)c * VOXELS + (size_t)zy * 64 + x];
    }
    __syncthreads();
    int c = t & 31, xg = t >> 5;
    const size_t base = ((size_t)q * VOXELS + (size_t)zy * 64) * 32;
    for (int xx = xg; xx < 64; xx += 8) {
        if (VT16) ((__hip_bfloat16*)vtp)[base + xx * 32 + c] = __float2bfloat16(buf[c][xx]);
        else      ((float*)vtp)[base + xx * 32 + c] = buf[c][xx];
    }
}

// ------------- weight pack: W[O][K] fp32 -> bf16 MFMA-B fragment order -------------
__global__ void k_prepw(const float* __restrict__ W, __hip_bfloat16* __restrict__ wf,
                        int O, int K, int conv_remap) {
    int n = blockIdx.x * blockDim.x + threadIdx.x;
    if (n >= O * K) return;
    int e = n & 7, lane = (n >> 3) & 63;
    int rest = n >> 9;
    int ksteps = K >> 5;
    int kstep = rest % ksteps, otile = rest / ksteps;
    int o = otile * 16 + (lane & 15);
    int k = kstep * 32 + (lane >> 4) * 8 + e;
    int ksrc = conv_remap ? ((k & 31) * 27 + (k >> 5)) : k;
    wf[n] = __float2bfloat16(W[(size_t)o * K + ksrc]);
}

// ================= spatial sort (counting sort by Morton cell) =================
__device__ __forceinline__ int point_cell(float px, float py, float pz) {
    int cx = min(63, max(0, (int)(px * 31.5f + 31.5f))) >> 3;
    int cy = min(63, max(0, (int)(py * 31.5f + 31.5f))) >> 3;
    int cz = min(63, max(0, (int)(pz * 31.5f + 31.5f))) >> 3;
    int k = 0;
#pragma unroll
    for (int b = 0; b < 3; ++b)
        k |= (((cx >> b) & 1) << (3 * b)) | (((cy >> b) & 1) << (3 * b + 1))
           | (((cz >> b) & 1) << (3 * b + 2));
    return k;
}

__global__ void k_hist(const float* __restrict__ xin, int* __restrict__ hist, int m) {
    int p = blockIdx.x * blockDim.x + threadIdx.x;
    if (p >= m) return;
    atomicAdd(&hist[point_cell(xin[p * 3], xin[p * 3 + 1], xin[p * 3 + 2])], 1);
}

__global__ __launch_bounds__(NCELL)
void k_scan(const int* __restrict__ hist, int* __restrict__ cursor) {
    __shared__ int sh[NCELL];
    int t = threadIdx.x;
    int v = hist[t];
    sh[t] = v;
    __syncthreads();
    for (int off = 1; off < NCELL; off <<= 1) {
        int u = (t >= off) ? sh[t - off] : 0;
        __syncthreads();
        sh[t] += u;
        __syncthreads();
    }
    cursor[t] = sh[t] - v;  // exclusive prefix
}

__global__ void k_scatter(const float* __restrict__ xin, int* __restrict__ cursor,
                          int* __restrict__ perm, int m) {
    int p = blockIdx.x * blockDim.x + threadIdx.x;
    if (p >= m) return;
    int cell = point_cell(xin[p * 3], xin[p * 3 + 1], xin[p * 3 + 2]);
    int pos = atomicAdd(&cursor[cell], 1);
    perm[pos] = p;
}

// ============ standalone sampler: 1 point/wave, 4 waves/block, no LDS ============
template <bool VT16, bool SORT>
__global__ __launch_bounds__(256, 8)
void k_sample(const float* __restrict__ xin, const void* __restrict__ vtp,
              const int* __restrict__ perm,
              __hip_bfloat16* __restrict__ fbuf, int m, int nblk) {
    // bijective XCD swizzle: contiguous chunk of sorted points per XCD (T1/m204)
    int b = blockIdx.x;
    {
        const int qd = nblk >> 3, r = nblk & 7;
        const int xcd = b & 7, i = b >> 3;
        b = (xcd < r) ? xcd * (qd + 1) + i : r * (qd + 1) + (xcd - r) * qd + i;
    }
    const int lane = threadIdx.x & 63;
    const int sp = b * 4 + (threadIdx.x >> 6);
    if (sp >= m) return;
    const int p = SORT ? perm[sp] : sp;

    const float px = xin[p * 3 + 0];
    const float py = xin[p * 3 + 1];
    const float pz = xin[p * 3 + 2];

    const int g  = lane & 7;
    const int cx = (lane >> 3) & 1;
    const int cy = (lane >> 4) & 1;
    const int cz = (lane >> 5) & 1;

    const float pxs = px * 31.5f + 31.5f;
    const float pys = py * 31.5f + 31.5f;
    const float pzs = pz * 31.5f + 31.5f;

    const int XS = VT16 ? 6 : 7;
    const int YS = VT16 ? 12 : 13;
    const int ZS = VT16 ? 18 : 19;
    const int QS = VT16 ? 24 : 25;
    const int GB = VT16 ? 8 : 16;

    int   xoS[4][3], yoS[4][3], zoS[4][3];
    float wxS[4][3], wyS[4][3], wzS[4][3];
#pragma unroll
    for (int q = 0; q < 4; ++q) {
        const float sc31 = (float)(2 << q) * (31.5f / 64.0f);
#pragma unroll
        for (int pos = 0; pos < 3; ++pos) {
            const float gv = (-2.0f + 1.5f * (float)pos) * sc31;
            {
                float ix = fminf(fmaxf(pxs + gv, 0.f), 63.f);
                float xf = floorf(ix); int x0 = (int)xf; float fx = ix - xf;
                int x1 = min(x0 + 1, 63);
                xoS[q][pos] = ((cx ? x1 : x0) << XS) + g * GB;
                wxS[q][pos] = cx ? fx : 1.f - fx;
            }
            {
                float iy = fminf(fmaxf(pys + gv, 0.f), 63.f);
                float yf = floorf(iy); int y0 = (int)yf; float fy = iy - yf;
                int y1 = min(y0 + 1, 63);
                yoS[q][pos] = (cy ? y1 : y0) << YS;
                wyS[q][pos] = cy ? fy : 1.f - fy;
            }
            {
                float iz = fminf(fmaxf(pzs + gv, 0.f), 63.f);
                float zf = floorf(iz); int z0 = (int)zf; float fz = iz - zf;
                int z1 = min(z0 + 1, 63);
                zoS[q][pos] = ((cz ? z1 : z0) << ZS) + (q << QS);
                wzS[q][pos] = cz ? fz : 1.f - fz;
            }
        }
    }

    const char* __restrict__ vtb = (const char*)vtp;
    __hip_bfloat16* __restrict__ frow = fbuf + (size_t)sp * 864;
#pragma unroll
    for (int j = 0; j < 3; ++j)
#pragma unroll
    for (int i = 0; i < 3; ++i)
#pragma unroll
    for (int k = 0; k < 3; ++k) {
        f32x4 acc = {0.f, 0.f, 0.f, 0.f};
#pragma unroll
        for (int q = 0; q < 4; ++q) {
            const int addr = zoS[q][k] + yoS[q][i] + xoS[q][j];
            f32x4 v;
            if (VT16) {
                short4v raw = *(const short4v*)(vtb + addr);
#pragma unroll
                for (int e = 0; e < 4; ++e)
                    v[e] = __uint_as_float(((unsigned)(unsigned short)raw[e]) << 16);
            } else {
                v = *(const f32x4*)(vtb + addr);
            }
            const float w = wzS[q][k] * wyS[q][i] * wxS[q][j];
#pragma unroll
            for (int r = 0; r < 4; ++r) acc[r] += w * v[r];
        }
#pragma unroll
        for (int r = 0; r < 4; ++r) {
            acc[r] += __shfl_xor(acc[r], 8);
            acc[r] += __shfl_xor(acc[r], 16);
            acc[r] += __shfl_xor(acc[r], 32);
        }
        if (lane < 8) {
            union { short4v v; __hip_bfloat16 h[4]; } u;
#pragma unroll
            for (int e = 0; e < 4; ++e) u.h[e] = __float2bfloat16(acc[e]);
            *(short4v*)(frow + (j * 9 + i * 3 + k) * 32 + lane * 4) = u.v;
        }
    }
}

// ============ MLP kernel: 16 (sorted) points/block; scatter to orig index ============
template <bool SORT>
__global__ __launch_bounds__(1024, 8)
void k_mlp(const float* __restrict__ xin, const __hip_bfloat16* __restrict__ fbuf,
           const int* __restrict__ perm,
           const __hip_bfloat16* __restrict__ w0f, const float* __restrict__ b0,
           const __hip_bfloat16* __restrict__ w1f, const float* __restrict__ b1,
           const float* __restrict__ fc1w, const float* __restrict__ fc1b,
           const __hip_bfloat16* __restrict__ w2f, const float* __restrict__ b2,
           const __hip_bfloat16* __restrict__ w3f, const float* __restrict__ b3,
           const float* __restrict__ fc4w, const float* __restrict__ fc4b,
           float* __restrict__ out, int m) {
    __shared__ __align__(16) __hip_bfloat16 zcat[16][ZC_PAD];
    __shared__ __align__(16) __hip_bfloat16 z0l[16][Z0_PAD];
    __shared__ __align__(16) __hip_bfloat16 z2l[16][Z2_PAD];
    __shared__ __align__(16) __hip_bfloat16 z3l[16][Z3_PAD];

    const int tid  = threadIdx.x;
    const int wave = tid >> 6;
    const int lane = tid & 63;
    const int p0   = blockIdx.x * 16;

    // ---- z_point = leaky(x @ fc1^T + b) -> zcat[:,0:128] ----
    {
        const int ptp = tid >> 6;
        const int ob  = tid & 63;
        const int sp  = min(p0 + ptp, m - 1);
        const int p   = SORT ? perm[sp] : sp;
        const float qx = xin[p * 3 + 0], qy = xin[p * 3 + 1], qz = xin[p * 3 + 2];
#pragma unroll
        for (int r = 0; r < 2; ++r) {
            const int o = ob + 64 * r;
            float v = qx * fc1w[o * 3 + 0] + qy * fc1w[o * 3 + 1] + qz * fc1w[o * 3 + 2] + fc1b[o];
            v = fmaxf(v, 0.2f * v);
            zcat[ptp][o] = __float2bfloat16(v);
        }
    }

    // ---- conv GEMM [16x864]x[864x64] (waves 0..3), A from global fbuf ----
    if (wave < 4) {
        f32x4 acc = {0.f, 0.f, 0.f, 0.f};
        const int row = lane & 15, g = lane >> 4;
        const int sr = min(p0 + row, m - 1);
        const __hip_bfloat16* arow = fbuf + (size_t)sr * 864;
        for (int ks = 0; ks < 27; ++ks) {
            short8 af = *(const short8*)(arow + ks * 32 + g * 8);
            short8 bf = *(const short8*)(w0f + (((size_t)wave * 27 + ks) * 64 + lane) * 8);
            acc = __builtin_amdgcn_mfma_f32_16x16x32_bf16(af, bf, acc, 0, 0, 0);
        }
        const int o = wave * 16 + row;
        const float bias = b0[o];
#pragma unroll
        for (int r = 0; r < 4; ++r)
            z0l[g * 4 + r][o] = __float2bfloat16(acc[r] + bias);
    }
    __syncthreads();

    // ---- lfc GEMM [16x64]x[64x128] (waves 0..7) -> zcat[:,128:256] ----
    if (wave < 8) {
        f32x4 acc = {0.f, 0.f, 0.f, 0.f};
        const int row = lane & 15, g = lane >> 4;
#pragma unroll
        for (int ks = 0; ks < 2; ++ks) {
            short8 af = *(const short8*)&z0l[row][ks * 32 + g * 8];
            short8 bf = *(const short8*)(w1f + (((size_t)wave * 2 + ks) * 64 + lane) * 8);
            acc = __builtin_amdgcn_mfma_f32_16x16x32_bf16(af, bf, acc, 0, 0, 0);
        }
        const int o = wave * 16 + row;
        const float bias = b1[o];
#pragma unroll
        for (int r = 0; r < 4; ++r)
            zcat[g * 4 + r][128 + o] = __float2bfloat16(acc[r] + bias);
    }
    __syncthreads();

    // ---- fc2 [16x256]x[256x512], leaky (16 waves x 2 tiles) ----
    {
        const int row = lane & 15, g = lane >> 4;
#pragma unroll
        for (int rt = 0; rt < 2; ++rt) {
            const int tile = wave * 2 + rt;
            f32x4 acc = {0.f, 0.f, 0.f, 0.f};
#pragma unroll
            for (int ks = 0; ks < 8; ++ks) {
                short8 af = *(const short8*)&zcat[row][ks * 32 + g * 8];
                short8 bf = *(const short8*)(w2f + (((size_t)tile * 8 + ks) * 64 + lane) * 8);
                acc = __builtin_amdgcn_mfma_f32_16x16x32_bf16(af, bf, acc, 0, 0, 0);
            }
            const int o = tile * 16 + row;
            const float bias = b2[o];
#pragma unroll
            for (int r = 0; r < 4; ++r) {
                float v = acc[r] + bias;
                v = fmaxf(v, 0.2f * v);
                z2l[g * 4 + r][o] = __float2bfloat16(v);
            }
        }
    }
    __syncthreads();

    // ---- fc3 [16x512]x[512x256], leaky (wave = tile) ----
    {
        const int row = lane & 15, g = lane >> 4;
        f32x4 acc = {0.f, 0.f, 0.f, 0.f};
        for (int ks = 0; ks < 16; ++ks) {
            short8 af = *(const short8*)&z2l[row][ks * 32 + g * 8];
            short8 bf = *(const short8*)(w3f + (((size_t)wave * 16 + ks) * 64 + lane) * 8);
            acc = __builtin_amdgcn_mfma_f32_16x16x32_bf16(af, bf, acc, 0, 0, 0);
        }
        const int o = wave * 16 + row;
        const float bias = b3[o];
#pragma unroll
        for (int r = 0; r < 4; ++r) {
            float v = acc[r] + bias;
            v = fmaxf(v, 0.2f * v);
            z3l[g * 4 + r][o] = __float2bfloat16(v);
        }
    }
    __syncthreads();

    // ---- fc4 [16x256]x[256x3] (waves 0..2, o = wave) ----
    if (wave < 3) {
        const int ptq = lane & 15, kg = lane >> 4;
        const int o = wave;
        float s = 0.f;
        for (int kk = 0; kk < 64; ++kk) {
            const int k = kg * 64 + kk;
            s += __bfloat162float(z3l[ptq][k]) * fc4w[o * 256 + k];
        }
        s += __shfl_xor(s, 16);
        s += __shfl_xor(s, 32);
        if (kg == 0) {
            const int spg = p0 + ptq;
            if (spg < m) {
                const int pg = SORT ? perm[spg] : spg;
                out[pg * 3 + o] = s + fc4b[o];
            }
        }
    }
}

extern "C" void kernel_launch(void* const* d_in, const int* in_sizes, int n_in,
                              void* d_out, int out_size, void* d_ws, size_t ws_size,
                              hipStream_t stream) {
    const float* x      = (const float*)d_in[1];
    const float* v0     = (const float*)d_in[2];
    const float* v1     = (const float*)d_in[3];
    const float* v2     = (const float*)d_in[4];
    const float* v3     = (const float*)d_in[5];
    const float* conv_w = (const float*)d_in[6];
    const float* conv_b = (const float*)d_in[7];
    const float* lfc_w  = (const float*)d_in[8];
    const float* lfc_b  = (const float*)d_in[9];
    const float* fc1_w  = (const float*)d_in[10];
    const float* fc1_b  = (const float*)d_in[11];
    const float* fc2_w  = (const float*)d_in[12];
    const float* fc2_b  = (const float*)d_in[13];
    const float* fc3_w  = (const float*)d_in[14];
    const float* fc3_b  = (const float*)d_in[15];
    const float* fc4_w  = (const float*)d_in[16];
    const float* fc4_b  = (const float*)d_in[17];
    float* out = (float*)d_out;
    const int m = in_sizes[1] / 3;

    char* ws = (char*)d_ws;
    size_t woff = 0;
    __hip_bfloat16* w0f = (__hip_bfloat16*)(ws + woff); woff += (size_t)55296 * 2;
    __hip_bfloat16* w1f = (__hip_bfloat16*)(ws + woff); woff += (size_t)8192 * 2;
    __hip_bfloat16* w2f = (__hip_bfloat16*)(ws + woff); woff += (size_t)131072 * 2;
    __hip_bfloat16* w3f = (__hip_bfloat16*)(ws + woff); woff += (size_t)131072 * 2;
    woff = (woff + 255) & ~(size_t)255;
    int* hist   = (int*)(ws + woff); woff += NCELL * 4;
    int* cursor = (int*)(ws + woff); woff += NCELL * 4;
    int* perm   = (int*)(ws + woff); woff += ((size_t)m * 4 + 255) & ~(size_t)255;

    const size_t vt32_bytes = (size_t)4 * VOXELS * 32 * 4;   // 128 MiB
    const size_t vt16_bytes = (size_t)4 * VOXELS * 32 * 2;   // 64 MiB
    const size_t fbytes     = ((size_t)m * 864 * 2 + 255) & ~(size_t)255;

    const size_t need_split16 = woff + vt16_bytes + fbytes;
    const size_t need_split32 = woff + vt32_bytes + fbytes;
    const size_t need_fused32 = woff + vt32_bytes;

    k_prepw<<<(55296 + 255) / 256, 256, 0, stream>>>(conv_w, w0f, 64, 864, 1);
    k_prepw<<<(8192 + 255) / 256, 256, 0, stream>>>(lfc_w, w1f, 128, 64, 0);
    k_prepw<<<(131072 + 255) / 256, 256, 0, stream>>>(fc2_w, w2f, 512, 256, 0);
    k_prepw<<<(131072 + 255) / 256, 256, 0, stream>>>(fc3_w, w3f, 256, 512, 0);

    const int nsb = (m + 3) / 4;
    const int nb  = (m + 15) / 16;
    const int npb = (m + 255) / 256;

    if (ws_size >= need_split16) {
        // ---- preferred: bf16 channel-last volumes + Morton-sorted points ----
        void* vt = (void*)(ws + woff);
        __hip_bfloat16* fbuf = (__hip_bfloat16*)(ws + woff + vt16_bytes);
        hipMemsetAsync(hist, 0, NCELL * 4, stream);
        k_hist<<<npb, 256, 0, stream>>>(x, hist, m);
        k_scan<<<1, NCELL, 0, stream>>>(hist, cursor);
        k_scatter<<<npb, 256, 0, stream>>>(x, cursor, perm, m);
        k_transpose<true><<<16384, 256, 0, stream>>>(v0, v1, v2, v3, vt);
        k_sample<true, true><<<nsb, 256, 0, stream>>>(x, vt, perm, fbuf, m, nsb);
        k_mlp<true><<<nb, 1024, 0, stream>>>(x, fbuf, perm, w0f, conv_b, w1f, lfc_b,
                                             fc1_w, fc1_b, w2f, fc2_b, w3f, fc3_b,
                                             fc4_w, fc4_b, out, m);
    } else if (ws_size >= need_split32) {
        void* vt = (void*)(ws + woff);
        __hip_bfloat16* fbuf = (__hip_bfloat16*)(ws + woff + vt32_bytes);
        k_transpose<false><<<16384, 256, 0, stream>>>(v0, v1, v2, v3, vt);
        k_sample<false, false><<<nsb, 256, 0, stream>>>(x, vt, perm, fbuf, m, nsb);
        k_mlp<false><<<nb, 1024, 0, stream>>>(x, fbuf, perm, w0f, conv_b, w1f, lfc_b,
                                              fc1_w, fc1_b, w2f, fc2_b, w3f, fc3_b,
                                              fc4_w, fc4_b, out, m);
    } else {
        // (small-ws fallback: sample straight from native layout, unsorted)
        __hip_bfloat16* fbuf = (__hip_bfloat16*)(ws + woff);
        k_sample<false, false><<<nsb, 256, 0, stream>>>(x, nullptr, perm, fbuf, m, nsb);
        k_mlp<false><<<nb, 1024, 0, stream>>>(x, fbuf, perm, w0f, conv_b, w1f, lfc_b,
                                              fc1_w, fc1_b, w2f, fc2_b, w3f, fc3_b,
                                              fc4_w, fc4_b, out, m);
    }
}

// Round 6
// 801.158 us; speedup vs baseline: 1.4259x; 1.0086x over previous
//
#include <hip/hip_runtime.h>
#include <hip/hip_bf16.h>

typedef __attribute__((ext_vector_type(8))) short short8;
typedef __attribute__((ext_vector_type(4))) short short4v;
typedef __attribute__((ext_vector_type(4))) float f32x4;

#define VOXELS 262144  // 64^3
#define F_PAD  872
#define ZC_PAD 264
#define Z0_PAD 72
#define Z2_PAD 520
#define Z3_PAD 264
#define NCELL  512     // 8x8x8 Morton cells

// ---------------- volume transpose: (C,D,H,W) -> (D,H,W,C) ----------------
template <bool VT16>
__global__ void k_transpose(const float* __restrict__ v0, const float* __restrict__ v1,
                            const float* __restrict__ v2, const float* __restrict__ v3,
                            void* __restrict__ vtp) {
    int b  = blockIdx.x;
    int q  = b >> 12;
    int zy = b & 4095;
    const float* src = (q == 0) ? v0 : (q == 1) ? v1 : (q == 2) ? v2 : v3;
    __shared__ float buf[32][65];
    int t = threadIdx.x;
    int x = t & 63, c0 = t >> 6;
    for (int cp = 0; cp < 32; cp += 4) {
        int c = c0 + cp;
        buf[c][x] = src[(size_t)c * VOXELS + (size_t)zy * 64 + x];
    }
    __syncthreads();
    int c = t & 31, xg = t >> 5;
    const size_t base = ((size_t)q * VOXELS + (size_t)zy * 64) * 32;
    for (int xx = xg; xx < 64; xx += 8) {
        if (VT16) ((__hip_bfloat16*)vtp)[base + xx * 32 + c] = __float2bfloat16(buf[c][xx]);
        else      ((float*)vtp)[base + xx * 32 + c] = buf[c][xx];
    }
}

// ------------- weight pack: W[O][K] fp32 -> bf16 MFMA-B fragment order -------------
__global__ void k_prepw(const float* __restrict__ W, __hip_bfloat16* __restrict__ wf,
                        int O, int K, int conv_remap) {
    int n = blockIdx.x * blockDim.x + threadIdx.x;
    if (n >= O * K) return;
    int e = n & 7, lane = (n >> 3) & 63;
    int rest = n >> 9;
    int ksteps = K >> 5;
    int kstep = rest % ksteps, otile = rest / ksteps;
    int o = otile * 16 + (lane & 15);
    int k = kstep * 32 + (lane >> 4) * 8 + e;
    int ksrc = conv_remap ? ((k & 31) * 27 + (k >> 5)) : k;
    wf[n] = __float2bfloat16(W[(size_t)o * K + ksrc]);
}

// ================= spatial sort (counting sort by Morton cell) =================
__device__ __forceinline__ int point_cell(float px, float py, float pz) {
    int cx = min(63, max(0, (int)(px * 31.5f + 31.5f))) >> 3;
    int cy = min(63, max(0, (int)(py * 31.5f + 31.5f))) >> 3;
    int cz = min(63, max(0, (int)(pz * 31.5f + 31.5f))) >> 3;
    int k = 0;
#pragma unroll
    for (int b = 0; b < 3; ++b)
        k |= (((cx >> b) & 1) << (3 * b)) | (((cy >> b) & 1) << (3 * b + 1))
           | (((cz >> b) & 1) << (3 * b + 2));
    return k;
}

__global__ void k_hist(const float* __restrict__ xin, int* __restrict__ hist, int m) {
    int p = blockIdx.x * blockDim.x + threadIdx.x;
    if (p >= m) return;
    atomicAdd(&hist[point_cell(xin[p * 3], xin[p * 3 + 1], xin[p * 3 + 2])], 1);
}

__global__ __launch_bounds__(NCELL)
void k_scan(const int* __restrict__ hist, int* __restrict__ cursor) {
    __shared__ int sh[NCELL];
    int t = threadIdx.x;
    int v = hist[t];
    sh[t] = v;
    __syncthreads();
    for (int off = 1; off < NCELL; off <<= 1) {
        int u = (t >= off) ? sh[t - off] : 0;
        __syncthreads();
        sh[t] += u;
        __syncthreads();
    }
    cursor[t] = sh[t] - v;  // exclusive prefix
}

__global__ void k_scatter(const float* __restrict__ xin, int* __restrict__ cursor,
                          int* __restrict__ perm, int m) {
    int p = blockIdx.x * blockDim.x + threadIdx.x;
    if (p >= m) return;
    int cell = point_cell(xin[p * 3], xin[p * 3 + 1], xin[p * 3 + 2]);
    int pos = atomicAdd(&cursor[cell], 1);
    perm[pos] = p;
}

// ============ standalone sampler: 1 point/wave, 4 waves/block ============
// Round-6 change: per-wave LDS row staging. Tap results (64 B each) go to an
// LDS row; the full 1728-B row is written to fbuf ONCE, densely, by all 64
// lanes (dwordx4). Round-5 killer: per-tap 64-B partial-line global stores
// thrashed L2 -> ~10x write amplification (WRITE_SIZE 937 MB vs 86 MB data).
template <bool VT16, bool SORT>
__global__ __launch_bounds__(256, 8)
void k_sample(const float* __restrict__ xin, const void* __restrict__ vtp,
              const int* __restrict__ perm,
              __hip_bfloat16* __restrict__ fbuf, int m, int nblk) {
    __shared__ __align__(16) __hip_bfloat16 rowbuf[4][896];  // 864 + pad, 1792 B/row

    // bijective XCD swizzle: contiguous chunk of sorted points per XCD (T1/m204)
    int b = blockIdx.x;
    {
        const int qd = nblk >> 3, r = nblk & 7;
        const int xcd = b & 7, i = b >> 3;
        b = (xcd < r) ? xcd * (qd + 1) + i : r * (qd + 1) + (xcd - r) * qd + i;
    }
    const int lane = threadIdx.x & 63;
    const int wv   = threadIdx.x >> 6;
    const int sp = b * 4 + wv;
    if (sp >= m) return;
    const int p = SORT ? perm[sp] : sp;

    const float px = xin[p * 3 + 0];
    const float py = xin[p * 3 + 1];
    const float pz = xin[p * 3 + 2];

    const int g  = lane & 7;
    const int cx = (lane >> 3) & 1;
    const int cy = (lane >> 4) & 1;
    const int cz = (lane >> 5) & 1;

    const float pxs = px * 31.5f + 31.5f;
    const float pys = py * 31.5f + 31.5f;
    const float pzs = pz * 31.5f + 31.5f;

    const int XS = VT16 ? 6 : 7;
    const int YS = VT16 ? 12 : 13;
    const int ZS = VT16 ? 18 : 19;
    const int QS = VT16 ? 24 : 25;
    const int GB = VT16 ? 8 : 16;

    int   xoS[4][3], yoS[4][3], zoS[4][3];
    float wxS[4][3], wyS[4][3], wzS[4][3];
#pragma unroll
    for (int q = 0; q < 4; ++q) {
        const float sc31 = (float)(2 << q) * (31.5f / 64.0f);
#pragma unroll
        for (int pos = 0; pos < 3; ++pos) {
            const float gv = (-2.0f + 1.5f * (float)pos) * sc31;
            {
                float ix = fminf(fmaxf(pxs + gv, 0.f), 63.f);
                float xf = floorf(ix); int x0 = (int)xf; float fx = ix - xf;
                int x1 = min(x0 + 1, 63);
                xoS[q][pos] = ((cx ? x1 : x0) << XS) + g * GB;
                wxS[q][pos] = cx ? fx : 1.f - fx;
            }
            {
                float iy = fminf(fmaxf(pys + gv, 0.f), 63.f);
                float yf = floorf(iy); int y0 = (int)yf; float fy = iy - yf;
                int y1 = min(y0 + 1, 63);
                yoS[q][pos] = (cy ? y1 : y0) << YS;
                wyS[q][pos] = cy ? fy : 1.f - fy;
            }
            {
                float iz = fminf(fmaxf(pzs + gv, 0.f), 63.f);
                float zf = floorf(iz); int z0 = (int)zf; float fz = iz - zf;
                int z1 = min(z0 + 1, 63);
                zoS[q][pos] = ((cz ? z1 : z0) << ZS) + (q << QS);
                wzS[q][pos] = cz ? fz : 1.f - fz;
            }
        }
    }

    const char* __restrict__ vtb = (const char*)vtp;
#pragma unroll
    for (int j = 0; j < 3; ++j)
#pragma unroll
    for (int i = 0; i < 3; ++i)
#pragma unroll
    for (int k = 0; k < 3; ++k) {
        f32x4 acc = {0.f, 0.f, 0.f, 0.f};
#pragma unroll
        for (int q = 0; q < 4; ++q) {
            const int addr = zoS[q][k] + yoS[q][i] + xoS[q][j];
            f32x4 v;
            if (VT16) {
                short4v raw = *(const short4v*)(vtb + addr);
#pragma unroll
                for (int e = 0; e < 4; ++e)
                    v[e] = __uint_as_float(((unsigned)(unsigned short)raw[e]) << 16);
            } else {
                v = *(const f32x4*)(vtb + addr);
            }
            const float w = wzS[q][k] * wyS[q][i] * wxS[q][j];
#pragma unroll
            for (int r = 0; r < 4; ++r) acc[r] += w * v[r];
        }
#pragma unroll
        for (int r = 0; r < 4; ++r) {
            acc[r] += __shfl_xor(acc[r], 8);
            acc[r] += __shfl_xor(acc[r], 16);
            acc[r] += __shfl_xor(acc[r], 32);
        }
        if (lane < 8) {
            union { short4v v; __hip_bfloat16 h[4]; } u;
#pragma unroll
            for (int e = 0; e < 4; ++e) u.h[e] = __float2bfloat16(acc[e]);
            *(short4v*)&rowbuf[wv][(j * 9 + i * 3 + k) * 32 + lane * 4] = u.v;
        }
    }

    // dense row write: 1728 B = 108 x dwordx4, contiguous; same-wave LDS
    // visibility only (no barrier needed)
    {
        const f32x4* __restrict__ lsrc = (const f32x4*)&rowbuf[wv][0];
        f32x4* __restrict__ gdst = (f32x4*)(fbuf + (size_t)sp * 864);
#pragma unroll
        for (int r = 0; r < 2; ++r) {
            const int idx = r * 64 + lane;
            if (idx < 108) gdst[idx] = lsrc[idx];
        }
    }
}

// ============ MLP kernel: 16 (sorted) points/block; scatter to orig index ============
template <bool SORT>
__global__ __launch_bounds__(1024, 8)
void k_mlp(const float* __restrict__ xin, const __hip_bfloat16* __restrict__ fbuf,
           const int* __restrict__ perm,
           const __hip_bfloat16* __restrict__ w0f, const float* __restrict__ b0,
           const __hip_bfloat16* __restrict__ w1f, const float* __restrict__ b1,
           const float* __restrict__ fc1w, const float* __restrict__ fc1b,
           const __hip_bfloat16* __restrict__ w2f, const float* __restrict__ b2,
           const __hip_bfloat16* __restrict__ w3f, const float* __restrict__ b3,
           const float* __restrict__ fc4w, const float* __restrict__ fc4b,
           float* __restrict__ out, int m) {
    __shared__ __align__(16) __hip_bfloat16 zcat[16][ZC_PAD];
    __shared__ __align__(16) __hip_bfloat16 z0l[16][Z0_PAD];
    __shared__ __align__(16) __hip_bfloat16 z2l[16][Z2_PAD];
    __shared__ __align__(16) __hip_bfloat16 z3l[16][Z3_PAD];

    const int tid  = threadIdx.x;
    const int wave = tid >> 6;
    const int lane = tid & 63;
    const int p0   = blockIdx.x * 16;

    // ---- z_point = leaky(x @ fc1^T + b) -> zcat[:,0:128] ----
    {
        const int ptp = tid >> 6;
        const int ob  = tid & 63;
        const int sp  = min(p0 + ptp, m - 1);
        const int p   = SORT ? perm[sp] : sp;
        const float qx = xin[p * 3 + 0], qy = xin[p * 3 + 1], qz = xin[p * 3 + 2];
#pragma unroll
        for (int r = 0; r < 2; ++r) {
            const int o = ob + 64 * r;
            float v = qx * fc1w[o * 3 + 0] + qy * fc1w[o * 3 + 1] + qz * fc1w[o * 3 + 2] + fc1b[o];
            v = fmaxf(v, 0.2f * v);
            zcat[ptp][o] = __float2bfloat16(v);
        }
    }

    // ---- conv GEMM [16x864]x[864x64] (waves 0..3), A from global fbuf ----
    if (wave < 4) {
        f32x4 acc = {0.f, 0.f, 0.f, 0.f};
        const int row = lane & 15, g = lane >> 4;
        const int sr = min(p0 + row, m - 1);
        const __hip_bfloat16* arow = fbuf + (size_t)sr * 864;
        for (int ks = 0; ks < 27; ++ks) {
            short8 af = *(const short8*)(arow + ks * 32 + g * 8);
            short8 bf = *(const short8*)(w0f + (((size_t)wave * 27 + ks) * 64 + lane) * 8);
            acc = __builtin_amdgcn_mfma_f32_16x16x32_bf16(af, bf, acc, 0, 0, 0);
        }
        const int o = wave * 16 + row;
        const float bias = b0[o];
#pragma unroll
        for (int r = 0; r < 4; ++r)
            z0l[g * 4 + r][o] = __float2bfloat16(acc[r] + bias);
    }
    __syncthreads();

    // ---- lfc GEMM [16x64]x[64x128] (waves 0..7) -> zcat[:,128:256] ----
    if (wave < 8) {
        f32x4 acc = {0.f, 0.f, 0.f, 0.f};
        const int row = lane & 15, g = lane >> 4;
#pragma unroll
        for (int ks = 0; ks < 2; ++ks) {
            short8 af = *(const short8*)&z0l[row][ks * 32 + g * 8];
            short8 bf = *(const short8*)(w1f + (((size_t)wave * 2 + ks) * 64 + lane) * 8);
            acc = __builtin_amdgcn_mfma_f32_16x16x32_bf16(af, bf, acc, 0, 0, 0);
        }
        const int o = wave * 16 + row;
        const float bias = b1[o];
#pragma unroll
        for (int r = 0; r < 4; ++r)
            zcat[g * 4 + r][128 + o] = __float2bfloat16(acc[r] + bias);
    }
    __syncthreads();

    // ---- fc2 [16x256]x[256x512], leaky (16 waves x 2 tiles) ----
    {
        const int row = lane & 15, g = lane >> 4;
#pragma unroll
        for (int rt = 0; rt < 2; ++rt) {
            const int tile = wave * 2 + rt;
            f32x4 acc = {0.f, 0.f, 0.f, 0.f};
#pragma unroll
            for (int ks = 0; ks < 8; ++ks) {
                short8 af = *(const short8*)&zcat[row][ks * 32 + g * 8];
                short8 bf = *(const short8*)(w2f + (((size_t)tile * 8 + ks) * 64 + lane) * 8);
                acc = __builtin_amdgcn_mfma_f32_16x16x32_bf16(af, bf, acc, 0, 0, 0);
            }
            const int o = tile * 16 + row;
            const float bias = b2[o];
#pragma unroll
            for (int r = 0; r < 4; ++r) {
                float v = acc[r] + bias;
                v = fmaxf(v, 0.2f * v);
                z2l[g * 4 + r][o] = __float2bfloat16(v);
            }
        }
    }
    __syncthreads();

    // ---- fc3 [16x512]x[512x256], leaky (wave = tile) ----
    {
        const int row = lane & 15, g = lane >> 4;
        f32x4 acc = {0.f, 0.f, 0.f, 0.f};
        for (int ks = 0; ks < 16; ++ks) {
            short8 af = *(const short8*)&z2l[row][ks * 32 + g * 8];
            short8 bf = *(const short8*)(w3f + (((size_t)wave * 16 + ks) * 64 + lane) * 8);
            acc = __builtin_amdgcn_mfma_f32_16x16x32_bf16(af, bf, acc, 0, 0, 0);
        }
        const int o = wave * 16 + row;
        const float bias = b3[o];
#pragma unroll
        for (int r = 0; r < 4; ++r) {
            float v = acc[r] + bias;
            v = fmaxf(v, 0.2f * v);
            z3l[g * 4 + r][o] = __float2bfloat16(v);
        }
    }
    __syncthreads();

    // ---- fc4 [16x256]x[256x3] (waves 0..2, o = wave) ----
    if (wave < 3) {
        const int ptq = lane & 15, kg = lane >> 4;
        const int o = wave;
        float s = 0.f;
        for (int kk = 0; kk < 64; ++kk) {
            const int k = kg * 64 + kk;
            s += __bfloat162float(z3l[ptq][k]) * fc4w[o * 256 + k];
        }
        s += __shfl_xor(s, 16);
        s += __shfl_xor(s, 32);
        if (kg == 0) {
            const int spg = p0 + ptq;
            if (spg < m) {
                const int pg = SORT ? perm[spg] : spg;
                out[pg * 3 + o] = s + fc4b[o];
            }
        }
    }
}

extern "C" void kernel_launch(void* const* d_in, const int* in_sizes, int n_in,
                              void* d_out, int out_size, void* d_ws, size_t ws_size,
                              hipStream_t stream) {
    const float* x      = (const float*)d_in[1];
    const float* v0     = (const float*)d_in[2];
    const float* v1     = (const float*)d_in[3];
    const float* v2     = (const float*)d_in[4];
    const float* v3     = (const float*)d_in[5];
    const float* conv_w = (const float*)d_in[6];
    const float* conv_b = (const float*)d_in[7];
    const float* lfc_w  = (const float*)d_in[8];
    const float* lfc_b  = (const float*)d_in[9];
    const float* fc1_w  = (const float*)d_in[10];
    const float* fc1_b  = (const float*)d_in[11];
    const float* fc2_w  = (const float*)d_in[12];
    const float* fc2_b  = (const float*)d_in[13];
    const float* fc3_w  = (const float*)d_in[14];
    const float* fc3_b  = (const float*)d_in[15];
    const float* fc4_w  = (const float*)d_in[16];
    const float* fc4_b  = (const float*)d_in[17];
    float* out = (float*)d_out;
    const int m = in_sizes[1] / 3;

    char* ws = (char*)d_ws;
    size_t woff = 0;
    __hip_bfloat16* w0f = (__hip_bfloat16*)(ws + woff); woff += (size_t)55296 * 2;
    __hip_bfloat16* w1f = (__hip_bfloat16*)(ws + woff); woff += (size_t)8192 * 2;
    __hip_bfloat16* w2f = (__hip_bfloat16*)(ws + woff); woff += (size_t)131072 * 2;
    __hip_bfloat16* w3f = (__hip_bfloat16*)(ws + woff); woff += (size_t)131072 * 2;
    woff = (woff + 255) & ~(size_t)255;
    int* hist   = (int*)(ws + woff); woff += NCELL * 4;
    int* cursor = (int*)(ws + woff); woff += NCELL * 4;
    int* perm   = (int*)(ws + woff); woff += ((size_t)m * 4 + 255) & ~(size_t)255;

    const size_t vt32_bytes = (size_t)4 * VOXELS * 32 * 4;   // 128 MiB
    const size_t vt16_bytes = (size_t)4 * VOXELS * 32 * 2;   // 64 MiB
    const size_t fbytes     = ((size_t)m * 864 * 2 + 255) & ~(size_t)255;

    const size_t need_split16 = woff + vt16_bytes + fbytes;
    const size_t need_split32 = woff + vt32_bytes + fbytes;

    k_prepw<<<(55296 + 255) / 256, 256, 0, stream>>>(conv_w, w0f, 64, 864, 1);
    k_prepw<<<(8192 + 255) / 256, 256, 0, stream>>>(lfc_w, w1f, 128, 64, 0);
    k_prepw<<<(131072 + 255) / 256, 256, 0, stream>>>(fc2_w, w2f, 512, 256, 0);
    k_prepw<<<(131072 + 255) / 256, 256, 0, stream>>>(fc3_w, w3f, 256, 512, 0);

    const int nsb = (m + 3) / 4;
    const int nb  = (m + 15) / 16;
    const int npb = (m + 255) / 256;

    if (ws_size >= need_split16) {
        // ---- preferred: bf16 channel-last volumes + Morton-sorted points ----
        void* vt = (void*)(ws + woff);
        __hip_bfloat16* fbuf = (__hip_bfloat16*)(ws + woff + vt16_bytes);
        hipMemsetAsync(hist, 0, NCELL * 4, stream);
        k_hist<<<npb, 256, 0, stream>>>(x, hist, m);
        k_scan<<<1, NCELL, 0, stream>>>(hist, cursor);
        k_scatter<<<npb, 256, 0, stream>>>(x, cursor, perm, m);
        k_transpose<true><<<16384, 256, 0, stream>>>(v0, v1, v2, v3, vt);
        k_sample<true, true><<<nsb, 256, 0, stream>>>(x, vt, perm, fbuf, m, nsb);
        k_mlp<true><<<nb, 1024, 0, stream>>>(x, fbuf, perm, w0f, conv_b, w1f, lfc_b,
                                             fc1_w, fc1_b, w2f, fc2_b, w3f, fc3_b,
                                             fc4_w, fc4_b, out, m);
    } else if (ws_size >= need_split32) {
        void* vt = (void*)(ws + woff);
        __hip_bfloat16* fbuf = (__hip_bfloat16*)(ws + woff + vt32_bytes);
        k_transpose<false><<<16384, 256, 0, stream>>>(v0, v1, v2, v3, vt);
        k_sample<false, false><<<nsb, 256, 0, stream>>>(x, vt, perm, fbuf, m, nsb);
        k_mlp<false><<<nb, 1024, 0, stream>>>(x, fbuf, perm, w0f, conv_b, w1f, lfc_b,
                                              fc1_w, fc1_b, w2f, fc2_b, w3f, fc3_b,
                                              fc4_w, fc4_b, out, m);
    } else {
        // (small-ws fallback: sample straight from native layout, unsorted)
        __hip_bfloat16* fbuf = (__hip_bfloat16*)(ws + woff);
        k_sample<false, false><<<nsb, 256, 0, stream>>>(x, nullptr, perm, fbuf, m, nsb);
        k_mlp<false><<<nb, 1024, 0, stream>>>(x, fbuf, perm, w0f, conv_b, w1f, lfc_b,
                                              fc1_w, fc1_b, w2f, fc2_b, w3f, fc3_b,
                                              fc4_w, fc4_b, out, m);
    }
}

// Round 7
// 499.527 us; speedup vs baseline: 2.2868x; 1.6038x over previous
//
#include <hip/hip_runtime.h>
#include <hip/hip_bf16.h>

typedef __attribute__((ext_vector_type(8))) short short8;
typedef __attribute__((ext_vector_type(4))) short short4v;
typedef __attribute__((ext_vector_type(4))) float f32x4;
typedef __attribute__((ext_vector_type(2))) float f32x2;

#define VOXELS 262144  // 64^3
#define ZC_PAD 264
#define Z0_PAD 72
#define Z2_PAD 520
#define Z3_PAD 264
#define NCELL  512     // 8x8x8 Morton cells

// ---------------- volume transpose: (C,D,H,W) -> (D,H,W,C) ----------------
template <bool VT16>
__global__ void k_transpose(const float* __restrict__ v0, const float* __restrict__ v1,
                            const float* __restrict__ v2, const float* __restrict__ v3,
                            void* __restrict__ vtp) {
    int b  = blockIdx.x;
    int q  = b >> 12;
    int zy = b & 4095;
    const float* src = (q == 0) ? v0 : (q == 1) ? v1 : (q == 2) ? v2 : v3;
    __shared__ float buf[32][65];
    int t = threadIdx.x;
    int x = t & 63, c0 = t >> 6;
    for (int cp = 0; cp < 32; cp += 4) {
        int c = c0 + cp;
        buf[c][x] = src[(size_t)c * VOXELS + (size_t)zy * 64 + x];
    }
    __syncthreads();
    int c = t & 31, xg = t >> 5;
    const size_t base = ((size_t)q * VOXELS + (size_t)zy * 64) * 32;
    for (int xx = xg; xx < 64; xx += 8) {
        if (VT16) ((__hip_bfloat16*)vtp)[base + xx * 32 + c] = __float2bfloat16(buf[c][xx]);
        else      ((float*)vtp)[base + xx * 32 + c] = buf[c][xx];
    }
}

// ------------- weight pack: W[O][K] fp32 -> bf16 MFMA-B fragment order -------------
__global__ void k_prepw(const float* __restrict__ W, __hip_bfloat16* __restrict__ wf,
                        int O, int K, int conv_remap) {
    int n = blockIdx.x * blockDim.x + threadIdx.x;
    if (n >= O * K) return;
    int e = n & 7, lane = (n >> 3) & 63;
    int rest = n >> 9;
    int ksteps = K >> 5;
    int kstep = rest % ksteps, otile = rest / ksteps;
    int o = otile * 16 + (lane & 15);
    int k = kstep * 32 + (lane >> 4) * 8 + e;
    int ksrc = conv_remap ? ((k & 31) * 27 + (k >> 5)) : k;
    wf[n] = __float2bfloat16(W[(size_t)o * K + ksrc]);
}

// ================= spatial sort (counting sort by Morton cell) =================
__device__ __forceinline__ int point_cell(float px, float py, float pz) {
    int cx = min(63, max(0, (int)(px * 31.5f + 31.5f))) >> 3;
    int cy = min(63, max(0, (int)(py * 31.5f + 31.5f))) >> 3;
    int cz = min(63, max(0, (int)(pz * 31.5f + 31.5f))) >> 3;
    int k = 0;
#pragma unroll
    for (int b = 0; b < 3; ++b)
        k |= (((cx >> b) & 1) << (3 * b)) | (((cy >> b) & 1) << (3 * b + 1))
           | (((cz >> b) & 1) << (3 * b + 2));
    return k;
}

__global__ void k_hist(const float* __restrict__ xin, int* __restrict__ hist, int m) {
    int p = blockIdx.x * blockDim.x + threadIdx.x;
    if (p >= m) return;
    atomicAdd(&hist[point_cell(xin[p * 3], xin[p * 3 + 1], xin[p * 3 + 2])], 1);
}

__global__ __launch_bounds__(NCELL)
void k_scan(const int* __restrict__ hist, int* __restrict__ cursor) {
    __shared__ int sh[NCELL];
    int t = threadIdx.x;
    int v = hist[t];
    sh[t] = v;
    __syncthreads();
    for (int off = 1; off < NCELL; off <<= 1) {
        int u = (t >= off) ? sh[t - off] : 0;
        __syncthreads();
        sh[t] += u;
        __syncthreads();
    }
    cursor[t] = sh[t] - v;  // exclusive prefix
}

__global__ void k_scatter(const float* __restrict__ xin, int* __restrict__ cursor,
                          int* __restrict__ perm, int m) {
    int p = blockIdx.x * blockDim.x + threadIdx.x;
    if (p >= m) return;
    int cell = point_cell(xin[p * 3], xin[p * 3 + 1], xin[p * 3 + 2]);
    int pos = atomicAdd(&cursor[cell], 1);
    perm[pos] = p;
}

// ============ standalone sampler: 1 point/wave, 4 waves/block ============
// Round-7 layout: pr=lane&15 -> bf16 channel PAIR (ch 2pr,2pr+1); bit4 = x
// corner, bit5 = y corner; z corners via 2 loads (register lerp). Per tap:
// 8 dword loads (1 VGPR each), 4 shfls (vs 12). __launch_bounds__(256,4)
// gives a 128-VGPR budget so ~5 taps' loads stay in flight (round-6 killer:
// VGPR_Count=32 -> ~3 outstanding loads/wave, latency-bound at 29% VALU).
// fbuf stores are non-temporal: keeps the 86-MB stream out of L2 so vt stays
// resident.
template <bool VT16, bool SORT>
__global__ __launch_bounds__(256, 4)
void k_sample(const float* __restrict__ xin, const void* __restrict__ vtp,
              const int* __restrict__ perm,
              __hip_bfloat16* __restrict__ fbuf, int m, int nblk) {
    __shared__ __align__(16) __hip_bfloat16 rowbuf[4][896];  // 864 + pad

    // bijective XCD swizzle: contiguous chunk of sorted points per XCD
    int b = blockIdx.x;
    {
        const int qd = nblk >> 3, r = nblk & 7;
        const int xcd = b & 7, i = b >> 3;
        b = (xcd < r) ? xcd * (qd + 1) + i : r * (qd + 1) + (xcd - r) * qd + i;
    }
    const int lane = threadIdx.x & 63;
    const int wv   = threadIdx.x >> 6;
    const int sp = b * 4 + wv;
    if (sp >= m) return;
    const int p = SORT ? perm[sp] : sp;

    const float px = xin[p * 3 + 0];
    const float py = xin[p * 3 + 1];
    const float pz = xin[p * 3 + 2];

    const int pr  = lane & 15;         // channel pair
    const int cxb = (lane >> 4) & 1;   // x corner
    const int cyb = (lane >> 5) & 1;   // y corner

    const float pxs = px * 31.5f + 31.5f;
    const float pys = py * 31.5f + 31.5f;
    const float pzs = pz * 31.5f + 31.5f;

    // byte shifts, channel-last: voxel line = 32ch*elt bytes
    const int XS  = VT16 ? 6 : 7;
    const int YS  = VT16 ? 12 : 13;
    const int ZS  = VT16 ? 18 : 19;
    const int QS  = VT16 ? 24 : 25;
    const int PRB = VT16 ? 4 : 8;      // bytes per channel pair

    int   xoS[4][3], yoS[4][3], zoS[4][3], zdS[4][3];
    float wxS[4][3], wyS[4][3], wzS[4][3];
#pragma unroll
    for (int q = 0; q < 4; ++q) {
        const float sc31 = (float)(2 << q) * (31.5f / 64.0f);
#pragma unroll
        for (int pos = 0; pos < 3; ++pos) {
            const float gv = (-2.0f + 1.5f * (float)pos) * sc31;  // compile-time
            {   // x axis: corner pre-selected by lane bit4
                float ix = fminf(fmaxf(pxs + gv, 0.f), 63.f);
                float xf = floorf(ix); int x0 = (int)xf; float fx = ix - xf;
                int x1 = min(x0 + 1, 63);
                xoS[q][pos] = ((cxb ? x1 : x0) << XS) + pr * PRB;
                wxS[q][pos] = cxb ? fx : 1.f - fx;
            }
            {   // y axis: corner pre-selected by lane bit5
                float iy = fminf(fmaxf(pys + gv, 0.f), 63.f);
                float yf = floorf(iy); int y0 = (int)yf; float fy = iy - yf;
                int y1 = min(y0 + 1, 63);
                yoS[q][pos] = (cyb ? y1 : y0) << YS;
                wyS[q][pos] = cyb ? fy : 1.f - fy;
            }
            {   // z axis: both corners in-register (2 loads + lerp)
                float iz = fminf(fmaxf(pzs + gv, 0.f), 63.f);
                float zf = floorf(iz); int z0 = (int)zf; float fz = iz - zf;
                int z1 = min(z0 + 1, 63);
                zoS[q][pos] = (z0 << ZS) + (q << QS);
                zdS[q][pos] = (z1 - z0) << ZS;
                wzS[q][pos] = fz;   // weight of z1 corner
            }
        }
    }

    const char* __restrict__ vtb = (const char*)vtp;
#pragma unroll
    for (int j = 0; j < 3; ++j)
#pragma unroll
    for (int i = 0; i < 3; ++i)
#pragma unroll
    for (int k = 0; k < 3; ++k) {
        float ax = 0.f, ay = 0.f;
#pragma unroll
        for (int q = 0; q < 4; ++q) {
            const int a0 = zoS[q][k] + yoS[q][i] + xoS[q][j];
            const int a1 = a0 + zdS[q][k];
            float v0x, v0y, v1x, v1y;
            if (VT16) {
                const unsigned r0 = *(const unsigned*)(vtb + a0);
                const unsigned r1 = *(const unsigned*)(vtb + a1);
                v0x = __uint_as_float(r0 << 16);
                v0y = __uint_as_float(r0 & 0xffff0000u);
                v1x = __uint_as_float(r1 << 16);
                v1y = __uint_as_float(r1 & 0xffff0000u);
            } else {
                const f32x2 r0 = *(const f32x2*)(vtb + a0);
                const f32x2 r1 = *(const f32x2*)(vtb + a1);
                v0x = r0.x; v0y = r0.y; v1x = r1.x; v1y = r1.y;
            }
            const float fz = wzS[q][k];
            const float tx = fmaf(fz, v1x - v0x, v0x);   // (1-fz)*v0 + fz*v1
            const float ty = fmaf(fz, v1y - v0y, v0y);
            const float wyx = wyS[q][i] * wxS[q][j];
            ax = fmaf(wyx, tx, ax);
            ay = fmaf(wyx, ty, ay);
        }
        // reduce over x (bit4) and y (bit5) corner lanes
        ax += __shfl_xor(ax, 16); ax += __shfl_xor(ax, 32);
        ay += __shfl_xor(ay, 16); ay += __shfl_xor(ay, 32);
        if (lane < 16) {
            const __hip_bfloat16 hx = __float2bfloat16(ax);
            const __hip_bfloat16 hy = __float2bfloat16(ay);
            const unsigned u = ((unsigned)*(const unsigned short*)&hy << 16)
                             |  (unsigned)*(const unsigned short*)&hx;
            ((unsigned*)&rowbuf[wv][0])[(j * 9 + i * 3 + k) * 16 + pr] = u;
        }
    }

    // dense row write: 1728 B = 108 x dwordx4, contiguous, NON-TEMPORAL
    {
        const f32x4* __restrict__ lsrc = (const f32x4*)&rowbuf[wv][0];
        f32x4* __restrict__ gdst = (f32x4*)(fbuf + (size_t)sp * 864);
#pragma unroll
        for (int r = 0; r < 2; ++r) {
            const int idx = r * 64 + lane;
            if (idx < 108) __builtin_nontemporal_store(lsrc[idx], &gdst[idx]);
        }
    }
}

// ============ MLP kernel: 16 (sorted) points/block; scatter to orig index ============
template <bool SORT>
__global__ __launch_bounds__(1024, 8)
void k_mlp(const float* __restrict__ xin, const __hip_bfloat16* __restrict__ fbuf,
           const int* __restrict__ perm,
           const __hip_bfloat16* __restrict__ w0f, const float* __restrict__ b0,
           const __hip_bfloat16* __restrict__ w1f, const float* __restrict__ b1,
           const float* __restrict__ fc1w, const float* __restrict__ fc1b,
           const __hip_bfloat16* __restrict__ w2f, const float* __restrict__ b2,
           const __hip_bfloat16* __restrict__ w3f, const float* __restrict__ b3,
           const float* __restrict__ fc4w, const float* __restrict__ fc4b,
           float* __restrict__ out, int m) {
    __shared__ __align__(16) __hip_bfloat16 zcat[16][ZC_PAD];
    __shared__ __align__(16) __hip_bfloat16 z0l[16][Z0_PAD];
    __shared__ __align__(16) __hip_bfloat16 z2l[16][Z2_PAD];
    __shared__ __align__(16) __hip_bfloat16 z3l[16][Z3_PAD];

    const int tid  = threadIdx.x;
    const int wave = tid >> 6;
    const int lane = tid & 63;
    const int p0   = blockIdx.x * 16;

    // ---- z_point = leaky(x @ fc1^T + b) -> zcat[:,0:128] ----
    {
        const int ptp = tid >> 6;
        const int ob  = tid & 63;
        const int sp  = min(p0 + ptp, m - 1);
        const int p   = SORT ? perm[sp] : sp;
        const float qx = xin[p * 3 + 0], qy = xin[p * 3 + 1], qz = xin[p * 3 + 2];
#pragma unroll
        for (int r = 0; r < 2; ++r) {
            const int o = ob + 64 * r;
            float v = qx * fc1w[o * 3 + 0] + qy * fc1w[o * 3 + 1] + qz * fc1w[o * 3 + 2] + fc1b[o];
            v = fmaxf(v, 0.2f * v);
            zcat[ptp][o] = __float2bfloat16(v);
        }
    }

    // ---- conv GEMM [16x864]x[864x64] (waves 0..3), A from global fbuf ----
    if (wave < 4) {
        f32x4 acc = {0.f, 0.f, 0.f, 0.f};
        const int row = lane & 15, g = lane >> 4;
        const int sr = min(p0 + row, m - 1);
        const __hip_bfloat16* arow = fbuf + (size_t)sr * 864;
        for (int ks = 0; ks < 27; ++ks) {
            short8 af = *(const short8*)(arow + ks * 32 + g * 8);
            short8 bf = *(const short8*)(w0f + (((size_t)wave * 27 + ks) * 64 + lane) * 8);
            acc = __builtin_amdgcn_mfma_f32_16x16x32_bf16(af, bf, acc, 0, 0, 0);
        }
        const int o = wave * 16 + row;
        const float bias = b0[o];
#pragma unroll
        for (int r = 0; r < 4; ++r)
            z0l[g * 4 + r][o] = __float2bfloat16(acc[r] + bias);
    }
    __syncthreads();

    // ---- lfc GEMM [16x64]x[64x128] (waves 0..7) -> zcat[:,128:256] ----
    if (wave < 8) {
        f32x4 acc = {0.f, 0.f, 0.f, 0.f};
        const int row = lane & 15, g = lane >> 4;
#pragma unroll
        for (int ks = 0; ks < 2; ++ks) {
            short8 af = *(const short8*)&z0l[row][ks * 32 + g * 8];
            short8 bf = *(const short8*)(w1f + (((size_t)wave * 2 + ks) * 64 + lane) * 8);
            acc = __builtin_amdgcn_mfma_f32_16x16x32_bf16(af, bf, acc, 0, 0, 0);
        }
        const int o = wave * 16 + row;
        const float bias = b1[o];
#pragma unroll
        for (int r = 0; r < 4; ++r)
            zcat[g * 4 + r][128 + o] = __float2bfloat16(acc[r] + bias);
    }
    __syncthreads();

    // ---- fc2 [16x256]x[256x512], leaky (16 waves x 2 tiles) ----
    {
        const int row = lane & 15, g = lane >> 4;
#pragma unroll
        for (int rt = 0; rt < 2; ++rt) {
            const int tile = wave * 2 + rt;
            f32x4 acc = {0.f, 0.f, 0.f, 0.f};
#pragma unroll
            for (int ks = 0; ks < 8; ++ks) {
                short8 af = *(const short8*)&zcat[row][ks * 32 + g * 8];
                short8 bf = *(const short8*)(w2f + (((size_t)tile * 8 + ks) * 64 + lane) * 8);
                acc = __builtin_amdgcn_mfma_f32_16x16x32_bf16(af, bf, acc, 0, 0, 0);
            }
            const int o = tile * 16 + row;
            const float bias = b2[o];
#pragma unroll
            for (int r = 0; r < 4; ++r) {
                float v = acc[r] + bias;
                v = fmaxf(v, 0.2f * v);
                z2l[g * 4 + r][o] = __float2bfloat16(v);
            }
        }
    }
    __syncthreads();

    // ---- fc3 [16x512]x[512x256], leaky (wave = tile) ----
    {
        const int row = lane & 15, g = lane >> 4;
        f32x4 acc = {0.f, 0.f, 0.f, 0.f};
        for (int ks = 0; ks < 16; ++ks) {
            short8 af = *(const short8*)&z2l[row][ks * 32 + g * 8];
            short8 bf = *(const short8*)(w3f + (((size_t)wave * 16 + ks) * 64 + lane) * 8);
            acc = __builtin_amdgcn_mfma_f32_16x16x32_bf16(af, bf, acc, 0, 0, 0);
        }
        const int o = wave * 16 + row;
        const float bias = b3[o];
#pragma unroll
        for (int r = 0; r < 4; ++r) {
            float v = acc[r] + bias;
            v = fmaxf(v, 0.2f * v);
            z3l[g * 4 + r][o] = __float2bfloat16(v);
        }
    }
    __syncthreads();

    // ---- fc4 [16x256]x[256x3] (waves 0..2, o = wave) ----
    if (wave < 3) {
        const int ptq = lane & 15, kg = lane >> 4;
        const int o = wave;
        float s = 0.f;
        for (int kk = 0; kk < 64; ++kk) {
            const int k = kg * 64 + kk;
            s += __bfloat162float(z3l[ptq][k]) * fc4w[o * 256 + k];
        }
        s += __shfl_xor(s, 16);
        s += __shfl_xor(s, 32);
        if (kg == 0) {
            const int spg = p0 + ptq;
            if (spg < m) {
                const int pg = SORT ? perm[spg] : spg;
                out[pg * 3 + o] = s + fc4b[o];
            }
        }
    }
}

extern "C" void kernel_launch(void* const* d_in, const int* in_sizes, int n_in,
                              void* d_out, int out_size, void* d_ws, size_t ws_size,
                              hipStream_t stream) {
    const float* x      = (const float*)d_in[1];
    const float* v0     = (const float*)d_in[2];
    const float* v1     = (const float*)d_in[3];
    const float* v2     = (const float*)d_in[4];
    const float* v3     = (const float*)d_in[5];
    const float* conv_w = (const float*)d_in[6];
    const float* conv_b = (const float*)d_in[7];
    const float* lfc_w  = (const float*)d_in[8];
    const float* lfc_b  = (const float*)d_in[9];
    const float* fc1_w  = (const float*)d_in[10];
    const float* fc1_b  = (const float*)d_in[11];
    const float* fc2_w  = (const float*)d_in[12];
    const float* fc2_b  = (const float*)d_in[13];
    const float* fc3_w  = (const float*)d_in[14];
    const float* fc3_b  = (const float*)d_in[15];
    const float* fc4_w  = (const float*)d_in[16];
    const float* fc4_b  = (const float*)d_in[17];
    float* out = (float*)d_out;
    const int m = in_sizes[1] / 3;

    char* ws = (char*)d_ws;
    size_t woff = 0;
    __hip_bfloat16* w0f = (__hip_bfloat16*)(ws + woff); woff += (size_t)55296 * 2;
    __hip_bfloat16* w1f = (__hip_bfloat16*)(ws + woff); woff += (size_t)8192 * 2;
    __hip_bfloat16* w2f = (__hip_bfloat16*)(ws + woff); woff += (size_t)131072 * 2;
    __hip_bfloat16* w3f = (__hip_bfloat16*)(ws + woff); woff += (size_t)131072 * 2;
    woff = (woff + 255) & ~(size_t)255;
    int* hist   = (int*)(ws + woff); woff += NCELL * 4;
    int* cursor = (int*)(ws + woff); woff += NCELL * 4;
    int* perm   = (int*)(ws + woff); woff += ((size_t)m * 4 + 255) & ~(size_t)255;

    const size_t vt32_bytes = (size_t)4 * VOXELS * 32 * 4;   // 128 MiB
    const size_t vt16_bytes = (size_t)4 * VOXELS * 32 * 2;   // 64 MiB
    const size_t fbytes     = ((size_t)m * 864 * 2 + 255) & ~(size_t)255;

    const size_t need_split16 = woff + vt16_bytes + fbytes;
    const size_t need_split32 = woff + vt32_bytes + fbytes;

    k_prepw<<<(55296 + 255) / 256, 256, 0, stream>>>(conv_w, w0f, 64, 864, 1);
    k_prepw<<<(8192 + 255) / 256, 256, 0, stream>>>(lfc_w, w1f, 128, 64, 0);
    k_prepw<<<(131072 + 255) / 256, 256, 0, stream>>>(fc2_w, w2f, 512, 256, 0);
    k_prepw<<<(131072 + 255) / 256, 256, 0, stream>>>(fc3_w, w3f, 256, 512, 0);

    const int nsb = (m + 3) / 4;
    const int nb  = (m + 15) / 16;
    const int npb = (m + 255) / 256;

    if (ws_size >= need_split16) {
        // ---- preferred: bf16 channel-last volumes + Morton-sorted points ----
        void* vt = (void*)(ws + woff);
        __hip_bfloat16* fbuf = (__hip_bfloat16*)(ws + woff + vt16_bytes);
        hipMemsetAsync(hist, 0, NCELL * 4, stream);
        k_hist<<<npb, 256, 0, stream>>>(x, hist, m);
        k_scan<<<1, NCELL, 0, stream>>>(hist, cursor);
        k_scatter<<<npb, 256, 0, stream>>>(x, cursor, perm, m);
        k_transpose<true><<<16384, 256, 0, stream>>>(v0, v1, v2, v3, vt);
        k_sample<true, true><<<nsb, 256, 0, stream>>>(x, vt, perm, fbuf, m, nsb);
        k_mlp<true><<<nb, 1024, 0, stream>>>(x, fbuf, perm, w0f, conv_b, w1f, lfc_b,
                                             fc1_w, fc1_b, w2f, fc2_b, w3f, fc3_b,
                                             fc4_w, fc4_b, out, m);
    } else if (ws_size >= need_split32) {
        void* vt = (void*)(ws + woff);
        __hip_bfloat16* fbuf = (__hip_bfloat16*)(ws + woff + vt32_bytes);
        k_transpose<false><<<16384, 256, 0, stream>>>(v0, v1, v2, v3, vt);
        k_sample<false, false><<<nsb, 256, 0, stream>>>(x, vt, perm, fbuf, m, nsb);
        k_mlp<false><<<nb, 1024, 0, stream>>>(x, fbuf, perm, w0f, conv_b, w1f, lfc_b,
                                              fc1_w, fc1_b, w2f, fc2_b, w3f, fc3_b,
                                              fc4_w, fc4_b, out, m);
    } else {
        __hip_bfloat16* fbuf = (__hip_bfloat16*)(ws + woff);
        k_sample<false, false><<<nsb, 256, 0, stream>>>(x, nullptr, perm, fbuf, m, nsb);
        k_mlp<false><<<nb, 1024, 0, stream>>>(x, fbuf, perm, w0f, conv_b, w1f, lfc_b,
                                              fc1_w, fc1_b, w2f, fc2_b, w3f, fc3_b,
                                              fc4_w, fc4_b, out, m);
    }
}